// Round 1
// baseline (303.081 us; speedup 1.0000x reference)
//
#include <hip/hip_runtime.h>
#include <math.h>

// Problem constants
#define BATCH 32
#define H 512
#define W 512
#define OUTD 502          // 512 - 11 + 1
#define WS 11
#define TX 32             // output tile width
#define TY 32             // output tile height
#define IX 42             // input tile width  (TX + WS - 1)
#define IY 42             // input tile height (TY + WS - 1)

#define C1F 6.5025f       // (0.01*255)^2
#define C2F 58.5225f      // (0.03*255)^2
#define N_OUT_TOTAL 8064128.0   // 32 * 502 * 502

struct GW { float g[WS]; };

__global__ __launch_bounds__(256) void ssim_tile_kernel(
    const float* __restrict__ img1, const float* __restrict__ img2,
    double* __restrict__ acc, GW w)
{
    // LDS: luma tiles for both images + 5 horizontal-conv channels
    __shared__ float sA[IY][IX + 2];          // +2 pad (bank decorrelation)
    __shared__ float sB[IY][IX + 2];
    __shared__ float hc[5][IY][TX + 1];       // +1 pad
    __shared__ double wsum[4];

    const int tid  = threadIdx.x;
    const int c0   = blockIdx.x * TX;         // global output col start
    const int r0   = blockIdx.y * TY;         // global output row start (== input row start)
    const int b    = blockIdx.z;

    // ---- Phase 1: load luma tiles (42x42, zero-pad out of range; padded
    // region is never used by valid outputs) ----
    {
        const int tx = tid & 63;              // 64 lanes across columns (42 used)
        const int ty = tid >> 6;              // 4 row-groups
        if (tx < IX) {
            const int col = c0 + tx;
            for (int iy = ty; iy < IY; iy += 4) {
                const int row = r0 + iy;
                float la = 0.f, lb = 0.f;
                if (row < H && col < W) {
                    const size_t base = ((size_t)(b * H + row) * W + col) * 3;
                    float r1 = img1[base], g1 = img1[base + 1], b1 = img1[base + 2];
                    float r2 = img2[base], g2 = img2[base + 1], b2 = img2[base + 2];
                    r1 = (r1 + 1.f) * 127.5f; g1 = (g1 + 1.f) * 127.5f; b1 = (b1 + 1.f) * 127.5f;
                    r2 = (r2 + 1.f) * 127.5f; g2 = (g2 + 1.f) * 127.5f; b2 = (b2 + 1.f) * 127.5f;
                    la = (r1 * 65.738f + g1 * 129.057f + b1 * 25.064f) * (1.f / 256.f) + 16.f;
                    lb = (r2 * 65.738f + g2 * 129.057f + b2 * 25.064f) * (1.f / 256.f) + 16.f;
                }
                sA[iy][tx] = la;
                sB[iy][tx] = lb;
            }
        }
    }
    __syncthreads();

    // ---- Phase 2: horizontal Gaussian over {a, b, a^2, b^2, ab} ----
    {
        const int ox = tid & 31;
        const int ty = tid >> 5;              // 8 row-groups
        for (int iy = ty; iy < IY; iy += 8) {
            float s0 = 0.f, s1 = 0.f, s2 = 0.f, s3 = 0.f, s4 = 0.f;
            #pragma unroll
            for (int k = 0; k < WS; ++k) {
                const float gk = w.g[k];
                const float a = sA[iy][ox + k];
                const float c = sB[iy][ox + k];
                s0 += gk * a;
                s1 += gk * c;
                s2 += gk * a * a;
                s3 += gk * c * c;
                s4 += gk * a * c;
            }
            hc[0][iy][ox] = s0;
            hc[1][iy][ox] = s1;
            hc[2][iy][ox] = s2;
            hc[3][iy][ox] = s3;
            hc[4][iy][ox] = s4;
        }
    }
    __syncthreads();

    // ---- Phase 3: vertical Gaussian + SSIM map + thread-local sum ----
    double local = 0.0;
    {
        const int ox = tid & 31;
        const int ty = tid >> 5;
        const bool col_ok = (c0 + ox) < OUTD;
        for (int oy = ty; oy < TY; oy += 8) {
            if (col_ok && (r0 + oy) < OUTD) {
                float mu1 = 0.f, mu2 = 0.f, e11 = 0.f, e22 = 0.f, e12 = 0.f;
                #pragma unroll
                for (int k = 0; k < WS; ++k) {
                    const float gk = w.g[k];
                    mu1 += gk * hc[0][oy + k][ox];
                    mu2 += gk * hc[1][oy + k][ox];
                    e11 += gk * hc[2][oy + k][ox];
                    e22 += gk * hc[3][oy + k][ox];
                    e12 += gk * hc[4][oy + k][ox];
                }
                const float mu1s = mu1 * mu1;
                const float mu2s = mu2 * mu2;
                const float mu12 = mu1 * mu2;
                const float s1q = e11 - mu1s;
                const float s2q = e22 - mu2s;
                const float s12 = e12 - mu12;
                const float num = (2.f * mu12 + C1F) * (2.f * s12 + C2F);
                const float den = (mu1s + mu2s + C1F) * (s1q + s2q + C2F);
                local += (double)(num / den);
            }
        }
    }

    // ---- Phase 4: block reduction (wave shuffle -> LDS -> one atomic) ----
    for (int off = 32; off > 0; off >>= 1)
        local += __shfl_down(local, off, 64);
    const int lane = tid & 63;
    const int wv   = tid >> 6;
    if (lane == 0) wsum[wv] = local;
    __syncthreads();
    if (tid == 0) {
        const double t = wsum[0] + wsum[1] + wsum[2] + wsum[3];
        atomicAdd(acc, t);
    }
}

__global__ void ssim_finalize_kernel(const double* __restrict__ acc,
                                     float* __restrict__ out)
{
    out[0] = (float)(acc[0] / N_OUT_TOTAL);
}

extern "C" void kernel_launch(void* const* d_in, const int* in_sizes, int n_in,
                              void* d_out, int out_size, void* d_ws, size_t ws_size,
                              hipStream_t stream) {
    const float* img1 = (const float*)d_in[0];
    const float* img2 = (const float*)d_in[1];
    float* out = (float*)d_out;
    double* acc = (double*)d_ws;   // 8 bytes of workspace as the global accumulator

    // Gaussian window, computed exactly as the numpy reference (float32 ops)
    GW w;
    {
        float g[WS];
        float s = 0.f;
        for (int i = 0; i < WS; ++i) {
            const float x = (float)(i - WS / 2);
            g[i] = expf(-(x * x) / (2.f * 1.5f * 1.5f));
            s += g[i];
        }
        for (int i = 0; i < WS; ++i) w.g[i] = g[i] / s;
    }

    // Zero the accumulator (workspace is re-poisoned before every launch)
    hipMemsetAsync(d_ws, 0, sizeof(double), stream);

    dim3 grid((OUTD + TX - 1) / TX, (OUTD + TY - 1) / TY, BATCH);  // 16 x 16 x 32
    ssim_tile_kernel<<<grid, 256, 0, stream>>>(img1, img2, acc, w);
    ssim_finalize_kernel<<<1, 1, 0, stream>>>(acc, out);
}